// Round 4
// baseline (221.265 us; speedup 1.0000x reference)
//
#include <hip/hip_runtime.h>
#include <math.h>
#include <stdint.h>

#define BB 2
#define CC 2048
#define DD 1024
#define HH 16
#define DHH 64
#define HALF 32

typedef __attribute__((ext_vector_type(8))) short bf16x8;
typedef __attribute__((ext_vector_type(4))) float f32x4;
typedef unsigned int u32;

__device__ __forceinline__ ushort f2bf(float f) {
    uint32_t u = __builtin_bit_cast(uint32_t, f);
    u = (u + 0x7FFFu + ((u >> 16) & 1u)) >> 16;
    return (ushort)u;
}
__device__ __forceinline__ float bf2f(ushort u) {
    return __builtin_bit_cast(float, ((uint32_t)u) << 16);
}

// async global->LDS, 16B per lane; LDS dest = base(wave-uniform) + lane*16
__device__ __forceinline__ void gload16(const void* g, void* lds) {
    __builtin_amdgcn_global_load_lds(
        (const u32 __attribute__((address_space(1)))*)g,
        (u32 __attribute__((address_space(3)))*)lds, 16, 0, 0);
}

// ---------------- fp32 -> bf16 cast ----------------
__global__ __launch_bounds__(256) void cast_bf16_k(const float* __restrict__ src,
                                                   ushort* __restrict__ dst, int n8) {
    int id = blockIdx.x * 256 + threadIdx.x;
    if (id >= n8) return;
    float4 a = *reinterpret_cast<const float4*>(src + (size_t)id * 8);
    float4 b = *reinterpret_cast<const float4*>(src + (size_t)id * 8 + 4);
    bf16x8 o;
    o[0] = (short)f2bf(a.x); o[1] = (short)f2bf(a.y);
    o[2] = (short)f2bf(a.z); o[3] = (short)f2bf(a.w);
    o[4] = (short)f2bf(b.x); o[5] = (short)f2bf(b.y);
    o[6] = (short)f2bf(b.z); o[7] = (short)f2bf(b.w);
    *reinterpret_cast<bf16x8*>(dst + (size_t)id * 8) = o;
}

// ---------------- RoPE cos/sin table ----------------
__global__ __launch_bounds__(256) void rope_table_k(float* __restrict__ ct, float* __restrict__ st) {
    int idx = blockIdx.x * 256 + threadIdx.x;
    if (idx >= CC * HALF) return;
    int m = idx >> 5;
    int t = idx & 31;
    double theta_d = pow(10000.0, -2.0 * ((double)t - 1.0) / 64.0);
    float theta = (float)theta_d;
    float ang = (float)m * theta;
    ct[idx] = cosf(ang);
    st[idx] = sinf(ang);
}

// ---------------- QKV GEMM (bf16 MFMA) + fused RoPE rotation ----------------
// C[m][n] = sum_k x[m][k]*w[n][k]; writes q,k,qr,kr row-major [B,H,C,64], v transposed vT[bh][d][c]
__global__ __launch_bounds__(256) void qkv_gemm_mfma_k(const ushort* __restrict__ xb,
                                                       const ushort* __restrict__ wqb,
                                                       const float* __restrict__ ct,
                                                       const float* __restrict__ st,
                                                       ushort* __restrict__ q,
                                                       ushort* __restrict__ k,
                                                       ushort* __restrict__ qr,
                                                       ushort* __restrict__ kr,
                                                       ushort* __restrict__ vT) {
    __shared__ ushort Al[128 * 64];
    __shared__ ushort Bl[128 * 64];
    const int tid = threadIdx.x;
    const int w = tid >> 6, l = tid & 63;
    const int l15 = l & 15, lg = l >> 4;
    const int wr = w >> 1, wc = w & 1;
    const int m0 = blockIdx.x * 128, n0 = blockIdx.y * 128;
    const int lrow = l >> 3, lch = l & 7;

    f32x4 acc[4][4];
#pragma unroll
    for (int i = 0; i < 4; i++)
#pragma unroll
        for (int j = 0; j < 4; j++) acc[i][j] = (f32x4){0.f, 0.f, 0.f, 0.f};

    for (int k0 = 0; k0 < 1024; k0 += 64) {
        __syncthreads();
#pragma unroll
        for (int c = 0; c < 4; c++) {
            int row = w * 32 + c * 8 + lrow;
            int gch = (lch ^ (row & 7)) * 8;
            gload16(xb + (size_t)(m0 + row) * 1024 + k0 + gch, &Al[(w * 32 + c * 8) * 64]);
            gload16(wqb + (size_t)(n0 + row) * 1024 + k0 + gch, &Bl[(w * 32 + c * 8) * 64]);
        }
        __syncthreads();
#pragma unroll
        for (int kk = 0; kk < 2; kk++) {
            bf16x8 a[4], b[4];
#pragma unroll
            for (int mt = 0; mt < 4; mt++) {
                int row = wr * 64 + mt * 16 + l15;
                a[mt] = *reinterpret_cast<const bf16x8*>(&Al[row * 64 + ((kk * 4 + lg) ^ (row & 7)) * 8]);
            }
#pragma unroll
            for (int nt = 0; nt < 4; nt++) {
                int row = wc * 64 + nt * 16 + l15;
                b[nt] = *reinterpret_cast<const bf16x8*>(&Bl[row * 64 + ((kk * 4 + lg) ^ (row & 7)) * 8]);
            }
#pragma unroll
            for (int mt = 0; mt < 4; mt++)
#pragma unroll
                for (int nt = 0; nt < 4; nt++)
                    acc[mt][nt] = __builtin_amdgcn_mfma_f32_16x16x32_bf16(a[mt], b[nt], acc[mt][nt], 0, 0, 0);
        }
    }
#pragma unroll
    for (int mt = 0; mt < 4; mt++)
#pragma unroll
        for (int nt = 0; nt < 4; nt++) {
            int n = n0 + wc * 64 + nt * 16 + l15;
            int part = n >> 10;          // wave-uniform (16-blocks never straddle 1024)
            int d = n & 1023;
            int h = d >> 6, dd = d & 63;
            int mbase = m0 + wr * 64 + mt * 16 + lg * 4;
            int bb = mbase >> 11, cpos = mbase & 2047;
            if (part == 2) {
                ushort4 pk;
                pk.x = f2bf(acc[mt][nt][0]); pk.y = f2bf(acc[mt][nt][1]);
                pk.z = f2bf(acc[mt][nt][2]); pk.w = f2bf(acc[mt][nt][3]);
                *reinterpret_cast<ushort4*>(vT + (((size_t)bb * HH + h) * DHH + dd) * CC + cpos) = pk;
            } else {
                ushort* dstu = (part == 0) ? q : k;
                ushort* dstr = (part == 0) ? qr : kr;
                const float sgn = (dd & 1) ? -1.f : 1.f;
                const int t = dd >> 1;
#pragma unroll
                for (int r = 0; r < 4; r++) {
                    float val = acc[mt][nt][r];
                    float par = __shfl_xor(val, 1, 64);   // pair partner (dd^1) sits in lane l15^1
                    float c = ct[(cpos + r) * 32 + t];
                    float s = st[(cpos + r) * 32 + t];
                    float rot = val * c + sgn * par * s;  // even: e*c+o*s ; odd: o*c-e*s
                    size_t base = (((size_t)bb * HH + h) * CC + (cpos + r)) * DHH + dd;
                    dstu[base] = f2bf(val);
                    dstr[base] = f2bf(rot);
                }
            }
        }
}

// ---------------- fused attention (swapped QK^T + 2-phase pipelined staging) ----------------
#define PSTR 72
__global__ __launch_bounds__(256) void attn_mfma_k(const ushort* __restrict__ qg,
                                                   const ushort* __restrict__ kg,
                                                   const ushort* __restrict__ vTg,
                                                   const ushort* __restrict__ qrg,
                                                   const ushort* __restrict__ krg,
                                                   ushort* __restrict__ y) {
    __shared__ ushort Kl[2][64 * 64];
    __shared__ ushort Krl[2][64 * 64];
    __shared__ ushort Vt[2][64 * 64];
    __shared__ ushort Pl[4][16 * PSTR];

    const int tid = threadIdx.x;
    const int w = tid >> 6, l = tid & 63;
    const int l15 = l & 15, lg = l >> 4;
    const int lrow = l >> 3, lch = l & 7;
    const int bid = blockIdx.x;
    const int bh = bid >> 5;
    const int xt = bid & 31;
    const int tile = (bid & 512) ? (31 - xt) : xt;   // complementary load balance
    const int q0 = tile * 64;
    const ushort* qb  = qg  + (size_t)bh * CC * DHH;
    const ushort* kb  = kg  + (size_t)bh * CC * DHH;
    const ushort* vTb = vTg + (size_t)bh * DHH * CC;
    const ushort* qrb = qrg + (size_t)bh * CC * DHH;
    const ushort* krb = krg + (size_t)bh * CC * DHH;

    // Q fragments (used as MFMA B-operand; same per-lane bytes as A layout)
    bf16x8 qf[2], qrf[2];
#pragma unroll
    for (int kk = 0; kk < 2; kk++) {
        int row = q0 + w * 16 + l15;
        qf[kk]  = *reinterpret_cast<const bf16x8*>(qb  + (size_t)row * DHH + kk * 32 + lg * 8);
        qrf[kk] = *reinterpret_cast<const bf16x8*>(qrb + (size_t)row * DHH + kk * 32 + lg * 8);
    }

    f32x4 yacc[4];
#pragma unroll
    for (int nt = 0; nt < 4; nt++) yacc[nt] = (f32x4){0.f, 0.f, 0.f, 0.f};
    float dacc = 0.f;

#define STAGE(KT, BUF)                                                                     \
    {                                                                                      \
        const int sk0 = (KT) * 64;                                                         \
        const bool sneed = (sk0 <= q0 + 63);                                               \
        _Pragma("unroll")                                                                  \
        for (int c = 0; c < 2; c++) {                                                      \
            int row = w * 16 + c * 8 + lrow;                                               \
            int gch = (lch ^ (row & 7)) * 8;                                               \
            gload16(kb + (size_t)(sk0 + row) * DHH + gch, &Kl[BUF][(w * 16 + c * 8) * 64]);\
            if (sneed) {                                                                   \
                gload16(krb + (size_t)(sk0 + row) * DHH + gch, &Krl[BUF][(w * 16 + c * 8) * 64]); \
                gload16(vTb + (size_t)row * CC + sk0 + gch, &Vt[BUF][(w * 16 + c * 8) * 64]);     \
            }                                                                              \
        }                                                                                  \
    }

    STAGE(0, 0);
    __syncthreads();   // drains vmcnt: tile 0 resident
    int cur = 0;

    for (int kt = 0; kt < CC / 64; kt++) {
        if (kt + 1 < CC / 64) STAGE(kt + 1, cur ^ 1);   // issue next tile's loads EARLY
        const int k0 = kt * 64;
        const bool need = (k0 <= q0 + 63);

        // denominator: S^T = mfma(K, Q); each lane sums 16 exps for ONE q-row (l15)
#pragma unroll
        for (int nt = 0; nt < 4; nt++) {
            f32x4 s = (f32x4){0.f, 0.f, 0.f, 0.f};
#pragma unroll
            for (int kk = 0; kk < 2; kk++) {
                int krow = nt * 16 + l15;
                bf16x8 ka = *reinterpret_cast<const bf16x8*>(&Kl[cur][krow * 64 + ((kk * 4 + lg) ^ (krow & 7)) * 8]);
                s = __builtin_amdgcn_mfma_f32_16x16x32_bf16(ka, qf[kk], s, 0, 0, 0);
            }
#pragma unroll
            for (int r = 0; r < 4; r++) dacc += exp2f(s[r] * 0.1803368801f);
        }

        if (need) {
            const int qrow = q0 + w * 16 + l15;
#pragma unroll
            for (int nt = 0; nt < 4; nt++) {
                f32x4 s = (f32x4){0.f, 0.f, 0.f, 0.f};
#pragma unroll
                for (int kk = 0; kk < 2; kk++) {
                    int krow = nt * 16 + l15;
                    bf16x8 ka = *reinterpret_cast<const bf16x8*>(&Krl[cur][krow * 64 + ((kk * 4 + lg) ^ (krow & 7)) * 8]);
                    s = __builtin_amdgcn_mfma_f32_16x16x32_bf16(ka, qrf[kk], s, 0, 0, 0);
                }
                // lane holds 4 CONSECUTIVE keys (k0+nt*16+lg*4+r) of q-row l15 -> packed b64 write
                ushort pb[4];
#pragma unroll
                for (int r = 0; r < 4; r++) {
                    int key = k0 + nt * 16 + lg * 4 + r;
                    float p = (key <= qrow) ? exp2f(s[r] * 0.1803368801f) : 0.f;
                    pb[r] = f2bf(p);
                }
                uint2 pk;
                pk.x = (u32)pb[0] | ((u32)pb[1] << 16);
                pk.y = (u32)pb[2] | ((u32)pb[3] << 16);
                *reinterpret_cast<uint2*>(&Pl[w][l15 * PSTR + nt * 16 + lg * 4]) = pk;
            }
            // PV (un-swapped): A = P row=l15, B = Vt col=d
            bf16x8 pa[2];
#pragma unroll
            for (int kk2 = 0; kk2 < 2; kk2++)
                pa[kk2] = *reinterpret_cast<const bf16x8*>(&Pl[w][l15 * PSTR + kk2 * 32 + lg * 8]);
#pragma unroll
            for (int nt2 = 0; nt2 < 4; nt2++)
#pragma unroll
                for (int kk2 = 0; kk2 < 2; kk2++) {
                    int vrow = nt2 * 16 + l15;
                    bf16x8 bv = *reinterpret_cast<const bf16x8*>(&Vt[cur][vrow * 64 + ((kk2 * 4 + lg) ^ (vrow & 7)) * 8]);
                    yacc[nt2] = __builtin_amdgcn_mfma_f32_16x16x32_bf16(pa[kk2], bv, yacc[nt2], 0, 0, 0);
                }
        }
        __syncthreads();   // next tile resident (vmcnt drained), buf[cur] free for reuse
        cur ^= 1;
    }

    // den: reduce over lg groups (lanes l15, l15+16, l15+32, l15+48 hold disjoint key subsets)
    float den = dacc;
    den += __shfl_xor(den, 16, 64);
    den += __shfl_xor(den, 32, 64);

    const int b = bh >> 4, h = bh & 15;
#pragma unroll
    for (int r = 0; r < 4; r++) {
        float dr = __shfl(den, lg * 4 + r, 64);   // den for q-row lg*4+r
        float inv = 1.f / dr;
        int row = q0 + w * 16 + lg * 4 + r;
#pragma unroll
        for (int nt2 = 0; nt2 < 4; nt2++)
            y[((size_t)b * CC + row) * DD + h * DHH + nt2 * 16 + l15] = f2bf(yacc[nt2][r] * inv);
    }
#undef STAGE
}

// ---------------- output projection ----------------
__global__ __launch_bounds__(256) void out_proj_mfma_k(const ushort* __restrict__ yb,
                                                       const ushort* __restrict__ wob,
                                                       const float* __restrict__ bias,
                                                       float* __restrict__ out) {
    __shared__ ushort Al[128 * 64];
    __shared__ ushort Bl[128 * 64];
    const int tid = threadIdx.x;
    const int w = tid >> 6, l = tid & 63;
    const int l15 = l & 15, lg = l >> 4;
    const int wr = w >> 1, wc = w & 1;
    const int m0 = blockIdx.x * 128, n0 = blockIdx.y * 128;
    const int lrow = l >> 3, lch = l & 7;

    f32x4 acc[4][4];
#pragma unroll
    for (int i = 0; i < 4; i++)
#pragma unroll
        for (int j = 0; j < 4; j++) acc[i][j] = (f32x4){0.f, 0.f, 0.f, 0.f};

    for (int k0 = 0; k0 < 1024; k0 += 64) {
        __syncthreads();
#pragma unroll
        for (int c = 0; c < 4; c++) {
            int row = w * 32 + c * 8 + lrow;
            int gch = (lch ^ (row & 7)) * 8;
            gload16(yb + (size_t)(m0 + row) * 1024 + k0 + gch, &Al[(w * 32 + c * 8) * 64]);
            gload16(wob + (size_t)(n0 + row) * 1024 + k0 + gch, &Bl[(w * 32 + c * 8) * 64]);
        }
        __syncthreads();
#pragma unroll
        for (int kk = 0; kk < 2; kk++) {
            bf16x8 a[4], b[4];
#pragma unroll
            for (int mt = 0; mt < 4; mt++) {
                int row = wr * 64 + mt * 16 + l15;
                a[mt] = *reinterpret_cast<const bf16x8*>(&Al[row * 64 + ((kk * 4 + lg) ^ (row & 7)) * 8]);
            }
#pragma unroll
            for (int nt = 0; nt < 4; nt++) {
                int row = wc * 64 + nt * 16 + l15;
                b[nt] = *reinterpret_cast<const bf16x8*>(&Bl[row * 64 + ((kk * 4 + lg) ^ (row & 7)) * 8]);
            }
#pragma unroll
            for (int mt = 0; mt < 4; mt++)
#pragma unroll
                for (int nt = 0; nt < 4; nt++)
                    acc[mt][nt] = __builtin_amdgcn_mfma_f32_16x16x32_bf16(a[mt], b[nt], acc[mt][nt], 0, 0, 0);
        }
    }
#pragma unroll
    for (int mt = 0; mt < 4; mt++)
#pragma unroll
        for (int nt = 0; nt < 4; nt++) {
            int n = n0 + wc * 64 + nt * 16 + l15;
            float bv = bias[n];
#pragma unroll
            for (int r = 0; r < 4; r++) {
                int m = m0 + wr * 64 + mt * 16 + lg * 4 + r;
                out[(size_t)m * 1024 + n] = acc[mt][nt][r] + bv;
            }
        }
}

extern "C" void kernel_launch(void* const* d_in, const int* in_sizes, int n_in,
                              void* d_out, int out_size, void* d_ws, size_t ws_size,
                              hipStream_t stream) {
    (void)in_sizes; (void)n_in; (void)out_size; (void)ws_size;
    const float* x     = (const float*)d_in[0];
    const float* w_qkv = (const float*)d_in[1];
    const float* w_out = (const float*)d_in[2];
    const float* b_out = (const float*)d_in[3];
    float* out = (float*)d_out;

    char* p = (char*)d_ws;
    float* ct = (float*)p;  p += (size_t)CC * HALF * 4;
    float* st = (float*)p;  p += (size_t)CC * HALF * 4;
    ushort* xb  = (ushort*)p; p += (size_t)4096 * 1024 * 2;
    ushort* wqb = (ushort*)p; p += (size_t)3072 * 1024 * 2;
    ushort* wob = (ushort*)p; p += (size_t)1024 * 1024 * 2;
    const size_t TEN = (size_t)BB * HH * CC * DHH;  // 4,194,304
    ushort* qb = (ushort*)p; p += TEN * 2;
    ushort* kb = (ushort*)p; p += TEN * 2;
    ushort* vT = (ushort*)p; p += TEN * 2;
    ushort* qr = (ushort*)p; p += TEN * 2;
    ushort* kr = (ushort*)p; p += TEN * 2;
    ushort* yb = (ushort*)p; p += (size_t)4096 * 1024 * 2;

    cast_bf16_k<<<dim3(2048), dim3(256), 0, stream>>>(x, xb, 524288);
    cast_bf16_k<<<dim3(1536), dim3(256), 0, stream>>>(w_qkv, wqb, 393216);
    cast_bf16_k<<<dim3(512),  dim3(256), 0, stream>>>(w_out, wob, 131072);
    rope_table_k<<<dim3((CC * HALF) / 256), dim3(256), 0, stream>>>(ct, st);
    qkv_gemm_mfma_k<<<dim3(32, 24), dim3(256), 0, stream>>>(xb, wqb, ct, st, qb, kb, qr, kr, vT);
    attn_mfma_k<<<dim3(1024), dim3(256), 0, stream>>>(qb, kb, vT, qr, kr, yb);
    out_proj_mfma_k<<<dim3(32, 8), dim3(256), 0, stream>>>(yb, wob, b_out, out);
}

// Round 5
// 172.752 us; speedup vs baseline: 1.2808x; 1.2808x over previous
//
#include <hip/hip_runtime.h>
#include <math.h>
#include <stdint.h>

#define BB 2
#define CC 2048
#define DD 1024
#define HH 16
#define DHH 64
#define HALF 32

typedef __attribute__((ext_vector_type(8))) short bf16x8;
typedef __attribute__((ext_vector_type(4))) float f32x4;
typedef unsigned int u32;

__device__ __forceinline__ ushort f2bf(float f) {
    uint32_t u = __builtin_bit_cast(uint32_t, f);
    u = (u + 0x7FFFu + ((u >> 16) & 1u)) >> 16;
    return (ushort)u;
}

// async global->LDS, 16B per lane; LDS dest = base(wave-uniform) + lane*16
__device__ __forceinline__ void gload16(const void* g, void* lds) {
    __builtin_amdgcn_global_load_lds(
        (const u32 __attribute__((address_space(1)))*)g,
        (u32 __attribute__((address_space(3)))*)lds, 16, 0, 0);
}

// ---------------- fused fp32 -> bf16 cast of x, w_qkv, w_out ----------------
__global__ __launch_bounds__(256) void cast3_k(const float* __restrict__ x,
                                               const float* __restrict__ wq,
                                               const float* __restrict__ wo,
                                               ushort* __restrict__ xb,
                                               ushort* __restrict__ wqb,
                                               ushort* __restrict__ wob) {
    int id = blockIdx.x * 256 + threadIdx.x;   // 1,048,576 total tasks of 8 elems
    const float* s;
    ushort* d;
    int off;
    if (id < 524288)       { s = x;  d = xb;  off = id; }
    else if (id < 917504)  { s = wq; d = wqb; off = id - 524288; }
    else                   { s = wo; d = wob; off = id - 917504; }
    float4 a = *reinterpret_cast<const float4*>(s + (size_t)off * 8);
    float4 b = *reinterpret_cast<const float4*>(s + (size_t)off * 8 + 4);
    bf16x8 o;
    o[0] = (short)f2bf(a.x); o[1] = (short)f2bf(a.y);
    o[2] = (short)f2bf(a.z); o[3] = (short)f2bf(a.w);
    o[4] = (short)f2bf(b.x); o[5] = (short)f2bf(b.y);
    o[6] = (short)f2bf(b.z); o[7] = (short)f2bf(b.w);
    *reinterpret_cast<bf16x8*>(d + (size_t)off * 8) = o;
}

// ---------------- RoPE cos/sin table ----------------
__global__ __launch_bounds__(256) void rope_table_k(float* __restrict__ ct, float* __restrict__ st) {
    int idx = blockIdx.x * 256 + threadIdx.x;
    if (idx >= CC * HALF) return;
    int m = idx >> 5;
    int t = idx & 31;
    double theta_d = pow(10000.0, -2.0 * ((double)t - 1.0) / 64.0);
    float theta = (float)theta_d;
    float ang = (float)m * theta;
    ct[idx] = cosf(ang);
    st[idx] = sinf(ang);
}

// ---------------- QKV GEMM (bf16 MFMA) + fused RoPE rotation ----------------
// q,k,qr,kr row-major [B,H,C,64]; v tiled-transposed vT3[bh][kt=32][64 d][64 k]
__global__ __launch_bounds__(256) void qkv_gemm_mfma_k(const ushort* __restrict__ xb,
                                                       const ushort* __restrict__ wqb,
                                                       const float* __restrict__ ct,
                                                       const float* __restrict__ st,
                                                       ushort* __restrict__ q,
                                                       ushort* __restrict__ k,
                                                       ushort* __restrict__ qr,
                                                       ushort* __restrict__ kr,
                                                       ushort* __restrict__ vT3) {
    __shared__ ushort Al[128 * 64];
    __shared__ ushort Bl[128 * 64];
    const int tid = threadIdx.x;
    const int w = tid >> 6, l = tid & 63;
    const int l15 = l & 15, lg = l >> 4;
    const int wr = w >> 1, wc = w & 1;
    const int m0 = blockIdx.x * 128, n0 = blockIdx.y * 128;
    const int lrow = l >> 3, lch = l & 7;

    f32x4 acc[4][4];
#pragma unroll
    for (int i = 0; i < 4; i++)
#pragma unroll
        for (int j = 0; j < 4; j++) acc[i][j] = (f32x4){0.f, 0.f, 0.f, 0.f};

    for (int k0 = 0; k0 < 1024; k0 += 64) {
        __syncthreads();
#pragma unroll
        for (int c = 0; c < 4; c++) {
            int row = w * 32 + c * 8 + lrow;
            int gch = (lch ^ (row & 7)) * 8;
            gload16(xb + (size_t)(m0 + row) * 1024 + k0 + gch, &Al[(w * 32 + c * 8) * 64]);
            gload16(wqb + (size_t)(n0 + row) * 1024 + k0 + gch, &Bl[(w * 32 + c * 8) * 64]);
        }
        __syncthreads();
#pragma unroll
        for (int kk = 0; kk < 2; kk++) {
            bf16x8 a[4], b[4];
#pragma unroll
            for (int mt = 0; mt < 4; mt++) {
                int row = wr * 64 + mt * 16 + l15;
                a[mt] = *reinterpret_cast<const bf16x8*>(&Al[row * 64 + ((kk * 4 + lg) ^ (row & 7)) * 8]);
            }
#pragma unroll
            for (int nt = 0; nt < 4; nt++) {
                int row = wc * 64 + nt * 16 + l15;
                b[nt] = *reinterpret_cast<const bf16x8*>(&Bl[row * 64 + ((kk * 4 + lg) ^ (row & 7)) * 8]);
            }
#pragma unroll
            for (int mt = 0; mt < 4; mt++)
#pragma unroll
                for (int nt = 0; nt < 4; nt++)
                    acc[mt][nt] = __builtin_amdgcn_mfma_f32_16x16x32_bf16(a[mt], b[nt], acc[mt][nt], 0, 0, 0);
        }
    }
#pragma unroll
    for (int mt = 0; mt < 4; mt++)
#pragma unroll
        for (int nt = 0; nt < 4; nt++) {
            int n = n0 + wc * 64 + nt * 16 + l15;
            int part = n >> 10;          // wave-uniform
            int d = n & 1023;
            int h = d >> 6, dd = d & 63;
            int mbase = m0 + wr * 64 + mt * 16 + lg * 4;
            int bb = mbase >> 11, cpos = mbase & 2047;
            if (part == 2) {
                // vT3[(bh*32 + kt)*64 + dd][kcol..kcol+3]
                int kt = cpos >> 6, kcol = cpos & 63;
                ushort4 pk;
                pk.x = f2bf(acc[mt][nt][0]); pk.y = f2bf(acc[mt][nt][1]);
                pk.z = f2bf(acc[mt][nt][2]); pk.w = f2bf(acc[mt][nt][3]);
                size_t off = ((((size_t)(bb * HH + h)) * 32 + kt) * 64 + dd) * 64 + kcol;
                *reinterpret_cast<ushort4*>(vT3 + off) = pk;
            } else {
                ushort* dstu = (part == 0) ? q : k;
                ushort* dstr = (part == 0) ? qr : kr;
                const float sgn = (dd & 1) ? -1.f : 1.f;
                const int t = dd >> 1;
#pragma unroll
                for (int r = 0; r < 4; r++) {
                    float val = acc[mt][nt][r];
                    float par = __shfl_xor(val, 1, 64);   // pair partner (dd^1) in lane l15^1
                    float c = ct[(cpos + r) * 32 + t];
                    float s = st[(cpos + r) * 32 + t];
                    float rot = val * c + sgn * par * s;  // even: e*c+o*s ; odd: o*c-e*s
                    size_t base = (((size_t)bb * HH + h) * CC + (cpos + r)) * DHH + dd;
                    dstu[base] = f2bf(val);
                    dstr[base] = f2bf(rot);
                }
            }
        }
}

// ---------------- fused attention ----------------
// swapped QK^T; K/Kr double-buffered LDS (pipelined); V direct global->reg (tiled layout);
// P per-wave swizzled [16][64]; diagonal-only masking.
__global__ __launch_bounds__(256, 4) void attn_mfma_k(const ushort* __restrict__ qg,
                                                      const ushort* __restrict__ kg,
                                                      const ushort* __restrict__ vT3,
                                                      const ushort* __restrict__ qrg,
                                                      const ushort* __restrict__ krg,
                                                      ushort* __restrict__ y) {
    __shared__ ushort Kl[2][64 * 64];
    __shared__ ushort Krl[2][64 * 64];
    __shared__ ushort Pl[4][16 * 64];

    const int tid = threadIdx.x;
    const int w = tid >> 6, l = tid & 63;
    const int l15 = l & 15, lg = l >> 4;
    const int lrow = l >> 3, lch = l & 7;
    const int bid = blockIdx.x;
    const int bh = bid >> 5;
    const int xt = bid & 31;
    const int tile = (bid & 512) ? (31 - xt) : xt;   // complementary load balance
    const int q0 = tile * 64;
    const ushort* qb  = qg  + (size_t)bh * CC * DHH;
    const ushort* kb  = kg  + (size_t)bh * CC * DHH;
    const ushort* qrb = qrg + (size_t)bh * CC * DHH;
    const ushort* krb = krg + (size_t)bh * CC * DHH;
    const ushort* vtb = vT3 + (size_t)bh * 32 * 64 * 64;

    // Q fragments (MFMA B-operand)
    bf16x8 qf[2], qrf[2];
#pragma unroll
    for (int kk = 0; kk < 2; kk++) {
        int row = q0 + w * 16 + l15;
        qf[kk]  = *reinterpret_cast<const bf16x8*>(qb  + (size_t)row * DHH + kk * 32 + lg * 8);
        qrf[kk] = *reinterpret_cast<const bf16x8*>(qrb + (size_t)row * DHH + kk * 32 + lg * 8);
    }

    f32x4 yacc[4];
#pragma unroll
    for (int nt = 0; nt < 4; nt++) yacc[nt] = (f32x4){0.f, 0.f, 0.f, 0.f};
    float dacc = 0.f;

#define STAGE(KT, BUF)                                                                        \
    {                                                                                         \
        const int sk0 = (KT) * 64;                                                            \
        const bool sneed = ((KT) <= tile);                                                    \
        _Pragma("unroll")                                                                     \
        for (int c = 0; c < 2; c++) {                                                         \
            int row = w * 16 + c * 8 + lrow;                                                  \
            int gch = (lch ^ (row & 7)) * 8;                                                  \
            gload16(kb + (size_t)(sk0 + row) * DHH + gch, &Kl[BUF][(w * 16 + c * 8) * 64]);   \
            if (sneed)                                                                        \
                gload16(krb + (size_t)(sk0 + row) * DHH + gch, &Krl[BUF][(w * 16 + c * 8) * 64]); \
        }                                                                                     \
    }

    STAGE(0, 0);
    __syncthreads();   // tile 0 resident
    int cur = 0;

    for (int kt = 0; kt < CC / 64; kt++) {
        const bool need = (kt <= tile);

        // V fragments for this tile: direct global->reg, 64B-coalesced (tiled layout).
        // Issued FIRST so the compiler's counted vmcnt wait for vf doesn't drain the prefetch.
        bf16x8 vf[4][2];
        if (need) {
            const ushort* vt0 = vtb + (size_t)kt * 64 * 64;
#pragma unroll
            for (int nt2 = 0; nt2 < 4; nt2++)
#pragma unroll
                for (int kk2 = 0; kk2 < 2; kk2++)
                    vf[nt2][kk2] = *reinterpret_cast<const bf16x8*>(
                        vt0 + (nt2 * 16 + l15) * 64 + kk2 * 32 + lg * 8);
        }

        if (kt + 1 < CC / 64) STAGE(kt + 1, cur ^ 1);   // prefetch next tile

        // ---- denominator: S^T = mfma(K, Q); lane sums 16 exps for q-row l15 ----
#pragma unroll
        for (int nt = 0; nt < 4; nt++) {
            f32x4 s = (f32x4){0.f, 0.f, 0.f, 0.f};
#pragma unroll
            for (int kk = 0; kk < 2; kk++) {
                int krow = nt * 16 + l15;
                bf16x8 ka = *reinterpret_cast<const bf16x8*>(
                    &Kl[cur][krow * 64 + ((kk * 4 + lg) ^ (krow & 7)) * 8]);
                s = __builtin_amdgcn_mfma_f32_16x16x32_bf16(ka, qf[kk], s, 0, 0, 0);
            }
#pragma unroll
            for (int r = 0; r < 4; r++)
                dacc += __builtin_amdgcn_exp2f(s[r] * 0.1803368801f);
        }

        if (need) {
            const bool diag = (kt == tile);
            const int qrow = q0 + w * 16 + l15;
            // ---- numerator -> P (swizzled per-wave [16][64]) ----
#pragma unroll
            for (int nt = 0; nt < 4; nt++) {
                f32x4 s = (f32x4){0.f, 0.f, 0.f, 0.f};
#pragma unroll
                for (int kk = 0; kk < 2; kk++) {
                    int krow = nt * 16 + l15;
                    bf16x8 ka = *reinterpret_cast<const bf16x8*>(
                        &Krl[cur][krow * 64 + ((kk * 4 + lg) ^ (krow & 7)) * 8]);
                    s = __builtin_amdgcn_mfma_f32_16x16x32_bf16(ka, qrf[kk], s, 0, 0, 0);
                }
                float pe[4];
#pragma unroll
                for (int r = 0; r < 4; r++)
                    pe[r] = __builtin_amdgcn_exp2f(s[r] * 0.1803368801f);
                if (diag) {
#pragma unroll
                    for (int r = 0; r < 4; r++) {
                        int key = kt * 64 + nt * 16 + lg * 4 + r;
                        pe[r] = (key <= qrow) ? pe[r] : 0.f;
                    }
                }
                u32 pk0, pk1;
                asm("v_cvt_pk_bf16_f32 %0, %1, %2" : "=v"(pk0) : "v"(pe[0]), "v"(pe[1]));
                asm("v_cvt_pk_bf16_f32 %0, %1, %2" : "=v"(pk1) : "v"(pe[2]), "v"(pe[3]));
                int swzc = (nt * 2 + (lg >> 1)) ^ (l15 & 7);
                uint2 pr; pr.x = pk0; pr.y = pk1;
                *reinterpret_cast<uint2*>(&Pl[w][l15 * 64 + swzc * 8 + (lg & 1) * 4]) = pr;
            }
            // ---- PV: A = P (this wave's rows), B = V from registers ----
            bf16x8 pa[2];
#pragma unroll
            for (int kk2 = 0; kk2 < 2; kk2++) {
                int rc = (kk2 * 4 + lg) ^ (l15 & 7);
                pa[kk2] = *reinterpret_cast<const bf16x8*>(&Pl[w][l15 * 64 + rc * 8]);
            }
#pragma unroll
            for (int nt2 = 0; nt2 < 4; nt2++)
#pragma unroll
                for (int kk2 = 0; kk2 < 2; kk2++)
                    yacc[nt2] = __builtin_amdgcn_mfma_f32_16x16x32_bf16(pa[kk2], vf[nt2][kk2],
                                                                        yacc[nt2], 0, 0, 0);
        }
        __syncthreads();   // next tile resident; buf[cur] reusable
        cur ^= 1;
    }

    // den: lanes l15, l15+16, l15+32, l15+48 hold disjoint key subsets of q-row l15
    float den = dacc;
    den += __shfl_xor(den, 16, 64);
    den += __shfl_xor(den, 32, 64);

    const int b = bh >> 4, h = bh & 15;
#pragma unroll
    for (int r = 0; r < 4; r++) {
        float dr = __shfl(den, lg * 4 + r, 64);   // den of q-row lg*4+r
        float inv = 1.f / dr;
        int row = q0 + w * 16 + lg * 4 + r;
#pragma unroll
        for (int nt2 = 0; nt2 < 4; nt2++)
            y[((size_t)b * CC + row) * DD + h * DHH + nt2 * 16 + l15] = f2bf(yacc[nt2][r] * inv);
    }
#undef STAGE
}

// ---------------- output projection ----------------
__global__ __launch_bounds__(256) void out_proj_mfma_k(const ushort* __restrict__ yb,
                                                       const ushort* __restrict__ wob,
                                                       const float* __restrict__ bias,
                                                       float* __restrict__ out) {
    __shared__ ushort Al[128 * 64];
    __shared__ ushort Bl[128 * 64];
    const int tid = threadIdx.x;
    const int w = tid >> 6, l = tid & 63;
    const int l15 = l & 15, lg = l >> 4;
    const int wr = w >> 1, wc = w & 1;
    const int m0 = blockIdx.x * 128, n0 = blockIdx.y * 128;
    const int lrow = l >> 3, lch = l & 7;

    f32x4 acc[4][4];
#pragma unroll
    for (int i = 0; i < 4; i++)
#pragma unroll
        for (int j = 0; j < 4; j++) acc[i][j] = (f32x4){0.f, 0.f, 0.f, 0.f};

    for (int k0 = 0; k0 < 1024; k0 += 64) {
        __syncthreads();
#pragma unroll
        for (int c = 0; c < 4; c++) {
            int row = w * 32 + c * 8 + lrow;
            int gch = (lch ^ (row & 7)) * 8;
            gload16(yb + (size_t)(m0 + row) * 1024 + k0 + gch, &Al[(w * 32 + c * 8) * 64]);
            gload16(wob + (size_t)(n0 + row) * 1024 + k0 + gch, &Bl[(w * 32 + c * 8) * 64]);
        }
        __syncthreads();
#pragma unroll
        for (int kk = 0; kk < 2; kk++) {
            bf16x8 a[4], b[4];
#pragma unroll
            for (int mt = 0; mt < 4; mt++) {
                int row = wr * 64 + mt * 16 + l15;
                a[mt] = *reinterpret_cast<const bf16x8*>(&Al[row * 64 + ((kk * 4 + lg) ^ (row & 7)) * 8]);
            }
#pragma unroll
            for (int nt = 0; nt < 4; nt++) {
                int row = wc * 64 + nt * 16 + l15;
                b[nt] = *reinterpret_cast<const bf16x8*>(&Bl[row * 64 + ((kk * 4 + lg) ^ (row & 7)) * 8]);
            }
#pragma unroll
            for (int mt = 0; mt < 4; mt++)
#pragma unroll
                for (int nt = 0; nt < 4; nt++)
                    acc[mt][nt] = __builtin_amdgcn_mfma_f32_16x16x32_bf16(a[mt], b[nt], acc[mt][nt], 0, 0, 0);
        }
    }
#pragma unroll
    for (int mt = 0; mt < 4; mt++)
#pragma unroll
        for (int nt = 0; nt < 4; nt++) {
            int n = n0 + wc * 64 + nt * 16 + l15;
            float bv = bias[n];
#pragma unroll
            for (int r = 0; r < 4; r++) {
                int m = m0 + wr * 64 + mt * 16 + lg * 4 + r;
                out[(size_t)m * 1024 + n] = acc[mt][nt][r] + bv;
            }
        }
}

extern "C" void kernel_launch(void* const* d_in, const int* in_sizes, int n_in,
                              void* d_out, int out_size, void* d_ws, size_t ws_size,
                              hipStream_t stream) {
    (void)in_sizes; (void)n_in; (void)out_size; (void)ws_size;
    const float* x     = (const float*)d_in[0];
    const float* w_qkv = (const float*)d_in[1];
    const float* w_out = (const float*)d_in[2];
    const float* b_out = (const float*)d_in[3];
    float* out = (float*)d_out;

    char* p = (char*)d_ws;
    float* ct = (float*)p;  p += (size_t)CC * HALF * 4;
    float* st = (float*)p;  p += (size_t)CC * HALF * 4;
    ushort* xb  = (ushort*)p; p += (size_t)4096 * 1024 * 2;
    ushort* wqb = (ushort*)p; p += (size_t)3072 * 1024 * 2;
    ushort* wob = (ushort*)p; p += (size_t)1024 * 1024 * 2;
    const size_t TEN = (size_t)BB * HH * CC * DHH;  // 4,194,304
    ushort* qb = (ushort*)p; p += TEN * 2;
    ushort* kb = (ushort*)p; p += TEN * 2;
    ushort* vT = (ushort*)p; p += TEN * 2;
    ushort* qr = (ushort*)p; p += TEN * 2;
    ushort* kr = (ushort*)p; p += TEN * 2;
    ushort* yb = (ushort*)p; p += (size_t)4096 * 1024 * 2;

    cast3_k<<<dim3(4096), dim3(256), 0, stream>>>(x, w_qkv, w_out, xb, wqb, wob);
    rope_table_k<<<dim3((CC * HALF) / 256), dim3(256), 0, stream>>>(ct, st);
    qkv_gemm_mfma_k<<<dim3(32, 24), dim3(256), 0, stream>>>(xb, wqb, ct, st, qb, kb, qr, kr, vT);
    attn_mfma_k<<<dim3(1024), dim3(256), 0, stream>>>(qb, kb, vT, qr, kr, yb);
    out_proj_mfma_k<<<dim3(32, 8), dim3(256), 0, stream>>>(yb, wob, b_out, out);
}